// Round 2
// baseline (823.757 us; speedup 1.0000x reference)
//
#include <hip/hip_runtime.h>

#define NPTS   300000
#define NPAIRS 100000
#define KOFF   27
#define NTOT   (KOFF * NPAIRS)      /* 2,700,000 */
#define CIN    32
#define COUT   64
#define NGROUP 8
#define EPSV   1e-5f
#define SLOPE  0.01f

#define PAIRS_PER_BLOCK 256
#define BLOCKS_PER_K ((NPAIRS + PAIRS_PER_BLOCK - 1) / PAIRS_PER_BLOCK)  /* 391 */

#define NB1 293                      /* ceil(300000/1024) scan blocks */

/* ---- workspace layout (bytes, 256-aligned) ---- */
#define OFS_STATS  0u
#define OFS_CURSOR 4096u
#define OFS_PART   (OFS_CURSOR + 1200128u)       /* 300000*4 rounded up */
#define OFS_PSLOT  (OFS_PART + 8192u)
#define OFS_SLOTS  (OFS_PSLOT + 10800128u)       /* 2.7M*4 rounded up */
#define OFS_FB16   (OFS_SLOTS + 345600000u)      /* 2.7M*64*2 */
#define WS_NEEDED  ((size_t)OFS_FB16 + 19200000u) /* + feats bf16 copy */

/* ---- bf16 helpers (round-to-nearest-even) ---- */
__device__ inline unsigned short f2b(float x) {
    unsigned u = __float_as_uint(x);
    u += 0x7FFFu + ((u >> 16) & 1u);
    return (unsigned short)(u >> 16);
}
__device__ inline float b2f_lo(unsigned d)  { return __uint_as_float(d << 16); }
__device__ inline float b2f_hi(unsigned d)  { return __uint_as_float(d & 0xFFFF0000u); }

/* ================= build kernels ================= */

__global__ __launch_bounds__(256) void to_bf16_kernel(const float2* __restrict__ src,
                                                      unsigned* __restrict__ dst, int n2) {
    int i = blockIdx.x * 256 + threadIdx.x;
    if (i < n2) {
        float2 v = src[i];
        dst[i] = (unsigned)f2b(v.x) | ((unsigned)f2b(v.y) << 16);
    }
}

__global__ __launch_bounds__(256) void zero_aux_kernel(int* __restrict__ cursor,
                                                       float* __restrict__ stats) {
    int i = blockIdx.x * 256 + threadIdx.x;
    if (i < NPTS) cursor[i] = 0;
    if (blockIdx.x == 0 && threadIdx.x < 16) stats[threadIdx.x] = 0.f;
}

__global__ __launch_bounds__(256) void hist_kernel(const int* __restrict__ oi,
                                                   int* __restrict__ cursor) {
    int i = blockIdx.x * 256 + threadIdx.x;
    if (i < NTOT) atomicAdd(cursor + oi[i], 1);
}

__global__ __launch_bounds__(256) void reduce_blocks_kernel(const int* __restrict__ cursor,
                                                            int* __restrict__ part) {
    __shared__ int sm[256];
    int tid = threadIdx.x, i0 = blockIdx.x * 1024 + tid * 4;
    int s = 0;
#pragma unroll
    for (int j = 0; j < 4; ++j) if (i0 + j < NPTS) s += cursor[i0 + j];
    sm[tid] = s; __syncthreads();
    for (int off = 128; off; off >>= 1) {
        if (tid < off) sm[tid] += sm[tid + off];
        __syncthreads();
    }
    if (tid == 0) part[blockIdx.x] = sm[0];
}

__global__ __launch_bounds__(512) void scan_partials_kernel(int* __restrict__ part) {
    __shared__ int sm[512];
    int tid = threadIdx.x;
    int v = (tid < NB1) ? part[tid] : 0;
    sm[tid] = v; __syncthreads();
    for (int off = 1; off < 512; off <<= 1) {
        int t = (tid >= off) ? sm[tid - off] : 0;
        __syncthreads();
        sm[tid] += t;
        __syncthreads();
    }
    if (tid < NB1) part[tid] = sm[tid] - v;   /* exclusive */
}

__global__ __launch_bounds__(256) void scan_apply_kernel(int* __restrict__ cursor,
                                                         const int* __restrict__ part) {
    __shared__ int sm[256];
    int tid = threadIdx.x, i0 = blockIdx.x * 1024 + tid * 4;
    int c0 = 0, c1 = 0, c2 = 0, c3 = 0;
    if (i0 + 0 < NPTS) c0 = cursor[i0 + 0];
    if (i0 + 1 < NPTS) c1 = cursor[i0 + 1];
    if (i0 + 2 < NPTS) c2 = cursor[i0 + 2];
    if (i0 + 3 < NPTS) c3 = cursor[i0 + 3];
    int s = c0 + c1 + c2 + c3;
    sm[tid] = s; __syncthreads();
    for (int off = 1; off < 256; off <<= 1) {
        int t = (tid >= off) ? sm[tid - off] : 0;
        __syncthreads();
        sm[tid] += t;
        __syncthreads();
    }
    int excl = sm[tid] - s + part[blockIdx.x];
    if (i0 + 0 < NPTS) cursor[i0 + 0] = excl;
    if (i0 + 1 < NPTS) cursor[i0 + 1] = excl + c0;
    if (i0 + 2 < NPTS) cursor[i0 + 2] = excl + c0 + c1;
    if (i0 + 3 < NPTS) cursor[i0 + 3] = excl + c0 + c1 + c2;
}

__global__ __launch_bounds__(256) void fill_kernel(const int* __restrict__ oi,
                                                   int* __restrict__ cursor,
                                                   int* __restrict__ pair_slot) {
    int i = blockIdx.x * 256 + threadIdx.x;
    if (i < NTOT) pair_slot[i] = atomicAdd(cursor + oi[i], 1);
    /* after this kernel: cursor[r] == end offset of row r */
}

/* ================= phase A: k-major compute into CSR slots (bf16) ================= */
__global__ __launch_bounds__(256) void convA_kernel(
    const unsigned* __restrict__ fb16, const float* __restrict__ weight,
    const int* __restrict__ in_idx, const int* __restrict__ pair_slot,
    unsigned short* __restrict__ slots16)
{
    const int lane = threadIdx.x & 63;
    const int wave = threadIdx.x >> 6;
    const int k     = blockIdx.x / BLOCKS_PER_K;
    const int pair0 = (blockIdx.x % BLOCKS_PER_K) * PAIRS_PER_BLOCK;

    float w[CIN];
    const float* wk = weight + k * (CIN * COUT) + lane;
#pragma unroll
    for (int i = 0; i < CIN; ++i) w[i] = wk[i * COUT];

    const int per_wave = PAIRS_PER_BLOCK / 4;
    int p    = pair0 + wave * per_wave;
    int pend = p + per_wave;
    if (pend > NPAIRS) pend = NPAIRS;

    const int* ii = in_idx    + k * NPAIRS;
    const int* ps = pair_slot + k * NPAIRS;

    for (; p < pend; ++p) {
        int rin  = __builtin_amdgcn_readfirstlane(ii[p]);
        int slot = __builtin_amdgcn_readfirstlane(ps[p]);
        const unsigned* fr = fb16 + rin * (CIN / 2);   /* 16 dwords, uniform */
        float acc = 0.f;
#pragma unroll
        for (int j = 0; j < CIN / 2; ++j) {
            unsigned d = fr[j];
            acc = fmaf(b2f_lo(d), w[2 * j],     acc);
            acc = fmaf(b2f_hi(d), w[2 * j + 1], acc);
        }
        slots16[(size_t)slot * COUT + lane] = f2b(acc);  /* full-line 128B store */
    }
}

/* ================= phase B: segmented reduce over CSR slots ================= */
__global__ __launch_bounds__(256) void reduceB_kernel(const unsigned short* __restrict__ slots16,
                                                      const int* __restrict__ ends,
                                                      float* __restrict__ out)
{
    const int lane = threadIdx.x & 63;
    const int row  = blockIdx.x * 4 + (threadIdx.x >> 6);
    if (row >= NPTS) return;
    int e = ends[row];
    int s = (row == 0) ? 0 : ends[row - 1];
    float acc = 0.f;
    for (; s < e; ++s)
        acc += __uint_as_float(((unsigned)slots16[(size_t)s * COUT + lane]) << 16);
    out[(size_t)row * COUT + lane] = acc;
}

/* ================= group stats ================= */
__global__ __launch_bounds__(256) void stats_kernel(const float* __restrict__ out,
                                                    float* __restrict__ stats) {
    const int c = threadIdx.x & 63;
    const int wave_in_grid = blockIdx.x * 4 + (threadIdx.x >> 6);
    const int nwaves = gridDim.x * 4;
    float s = 0.f, ss = 0.f;
    for (int r = wave_in_grid; r < NPTS; r += nwaves) {
        float v = out[(size_t)r * COUT + c];
        s += v; ss += v * v;
    }
#pragma unroll
    for (int m = 1; m < 8; m <<= 1) {
        s  += __shfl_xor(s,  m, 64);
        ss += __shfl_xor(ss, m, 64);
    }
    if ((c & 7) == 0) {
        int g = c >> 3;
        atomicAdd(stats + g,     s);
        atomicAdd(stats + 8 + g, ss);
    }
}

/* ================= normalize + affine + leaky relu ================= */
__global__ __launch_bounds__(256) void norm_kernel(float4* __restrict__ out4, int n4,
                                                   const float* __restrict__ stats,
                                                   const float* __restrict__ gamma,
                                                   const float* __restrict__ beta) {
    int i = blockIdx.x * blockDim.x + threadIdx.x;
    if (i >= n4) return;
    int c0 = (i & 15) * 4;
    int g  = c0 >> 3;
    const float cnt = (float)NPTS * (COUT / NGROUP);
    float mean = stats[g] / cnt;
    float var  = stats[8 + g] / cnt - mean * mean;
    float inv  = rsqrtf(var + EPSV);
    float4 v  = out4[i];
    float4 ga = *(const float4*)(gamma + c0);
    float4 be = *(const float4*)(beta  + c0);
    float x;
    x = (v.x - mean) * inv * ga.x + be.x; v.x = x >= 0.f ? x : SLOPE * x;
    x = (v.y - mean) * inv * ga.y + be.y; v.y = x >= 0.f ? x : SLOPE * x;
    x = (v.z - mean) * inv * ga.z + be.z; v.z = x >= 0.f ? x : SLOPE * x;
    x = (v.w - mean) * inv * ga.w + be.w; v.w = x >= 0.f ? x : SLOPE * x;
    out4[i] = v;
}

/* ================= fallback (round-1 path) ================= */
__global__ __launch_bounds__(256) void zero_out_kernel(float4* __restrict__ out4, int n4,
                                                       float* __restrict__ stats) {
    int i = blockIdx.x * blockDim.x + threadIdx.x;
    if (i < n4) out4[i] = make_float4(0.f, 0.f, 0.f, 0.f);
    if (blockIdx.x == 0 && threadIdx.x < 16) stats[threadIdx.x] = 0.f;
}

__global__ __launch_bounds__(256) void conv_atomic_kernel(
    const float* __restrict__ feats, const float* __restrict__ weight,
    const int* __restrict__ in_idx, const int* __restrict__ out_idx,
    float* __restrict__ out)
{
    const int lane = threadIdx.x & 63;
    const int wave = threadIdx.x >> 6;
    const int k     = blockIdx.x / BLOCKS_PER_K;
    const int pair0 = (blockIdx.x % BLOCKS_PER_K) * PAIRS_PER_BLOCK;
    float w[CIN];
    const float* wk = weight + k * (CIN * COUT) + lane;
#pragma unroll
    for (int i = 0; i < CIN; ++i) w[i] = wk[i * COUT];
    const int per_wave = PAIRS_PER_BLOCK / 4;
    int p = pair0 + wave * per_wave;
    int pend = p + per_wave;
    if (pend > NPAIRS) pend = NPAIRS;
    const int* ii = in_idx  + k * NPAIRS;
    const int* oi = out_idx + k * NPAIRS;
    for (; p < pend; ++p) {
        int rin  = __builtin_amdgcn_readfirstlane(ii[p]);
        int rout = __builtin_amdgcn_readfirstlane(oi[p]);
        const float* frow = feats + (size_t)rin * CIN;
        float acc = 0.f;
#pragma unroll
        for (int i = 0; i < CIN; ++i) acc = fmaf(frow[i], w[i], acc);
        atomicAdd(out + (size_t)rout * COUT + lane, acc);
    }
}

/* ================= launch ================= */
extern "C" void kernel_launch(void* const* d_in, const int* in_sizes, int n_in,
                              void* d_out, int out_size, void* d_ws, size_t ws_size,
                              hipStream_t stream) {
    const float* feats   = (const float*)d_in[0];
    const float* weight  = (const float*)d_in[1];
    const float* gamma   = (const float*)d_in[2];
    const float* beta    = (const float*)d_in[3];
    const int*   in_idx  = (const int*)d_in[4];
    const int*   out_idx = (const int*)d_in[5];
    float* out = (float*)d_out;

    char* ws = (char*)d_ws;
    float*          stats     = (float*)(ws + OFS_STATS);
    int*            cursor    = (int*)(ws + OFS_CURSOR);
    int*            part      = (int*)(ws + OFS_PART);
    int*            pair_slot = (int*)(ws + OFS_PSLOT);
    unsigned short* slots16   = (unsigned short*)(ws + OFS_SLOTS);
    unsigned*       fb16      = (unsigned*)(ws + OFS_FB16);

    int n4 = out_size / 4;
    int zb = (n4 + 255) / 256;

    if (ws_size >= WS_NEEDED) {
        int n2 = NPTS * CIN / 2;  /* 4.8M dword pairs */
        to_bf16_kernel<<<(n2 + 255) / 256, 256, 0, stream>>>((const float2*)feats, fb16, n2);
        zero_aux_kernel<<<(NPTS + 255) / 256, 256, 0, stream>>>(cursor, stats);
        hist_kernel<<<(NTOT + 255) / 256, 256, 0, stream>>>(out_idx, cursor);
        reduce_blocks_kernel<<<NB1, 256, 0, stream>>>(cursor, part);
        scan_partials_kernel<<<1, 512, 0, stream>>>(part);
        scan_apply_kernel<<<NB1, 256, 0, stream>>>(cursor, part);
        fill_kernel<<<(NTOT + 255) / 256, 256, 0, stream>>>(out_idx, cursor, pair_slot);
        convA_kernel<<<KOFF * BLOCKS_PER_K, 256, 0, stream>>>(fb16, weight, in_idx, pair_slot, slots16);
        reduceB_kernel<<<(NPTS + 3) / 4, 256, 0, stream>>>(slots16, cursor, out);
        stats_kernel<<<1024, 256, 0, stream>>>(out, stats);
        norm_kernel<<<zb, 256, 0, stream>>>((float4*)out, n4, stats, gamma, beta);
    } else {
        /* fallback: round-1 atomic path */
        zero_out_kernel<<<zb, 256, 0, stream>>>((float4*)out, n4, stats);
        conv_atomic_kernel<<<KOFF * BLOCKS_PER_K, 256, 0, stream>>>(feats, weight, in_idx, out_idx, out);
        stats_kernel<<<1024, 256, 0, stream>>>(out, stats);
        norm_kernel<<<zb, 256, 0, stream>>>((float4*)out, n4, stats, gamma, beta);
    }
}